// Round 8
// baseline (125.980 us; speedup 1.0000x reference)
//
#include <hip/hip_runtime.h>

// DiffuseLR v6: 6-kernel pipeline, zero device atomics.
//   fcT'[n][c] = dinv[n]*fc_w[c][n]          (pre-scaled, transposed weights)
//   gT[s][c]   = dinv[s]*(sum_{e:src=s} w_e*fcT'[dst_e][c] + fcT'[s][c])
//   logits = x @ gT + b; out = softmax(logits)

#define N_NODES   20000
#define N_EDGES_C 640000
#define N_CLASSES 30
#define CPAD      32

// deg-hist geometry
#define HBLKS     64
#define HNODES    10000
#define HEDGES    (N_EDGES_C / HBLKS)     // 10000

// partition geometry
#define BN        64                      // nodes per bucket
#define NBUCKET   313                     // ceil(20000/64)
#define NPB       (NBUCKET * BN)          // 20032
#define NSLAB     256
#define SLAB_E    (N_EDGES_C / NSLAB)     // 2500
#define NSCAN     (NBUCKET * NSLAB)       // 80128
#define ECAP      2600                    // per-bucket cap (mean 2048, sd ~45)

// gemm geometry
#define NCHUNK    64
#define NCHUNKS   313
#define XL_LD     130
#define GT_LD     68
#define GBX       128                     // gemm grid x; 3 strided chunks each

#define FCB       ((NPB * CPAD) / 256)    // 2504 fcT' blocks

// K1: (a) blocks [0,128): weighted in-degree LDS histogram per (edge-slab, half)
//     (b) blocks [128,384): src-bucket counts per slab (counting-sort pass 1)
__global__ __launch_bounds__(256) void k1_hists(const int* __restrict__ src,
        const int* __restrict__ dst, const float* __restrict__ w,
        float* __restrict__ degp, int* __restrict__ cnt) {
    __shared__ float h[HNODES];   // 40 KB (aliased as int bc[] in role b)
    int bid = blockIdx.x;
    if (bid < 2 * HBLKS) {
        int eb = bid >> 1, half = bid & 1;
        int nbase = half * HNODES;
        for (int i = threadIdx.x; i < HNODES; i += 256) h[i] = 0.f;
        __syncthreads();
        const int4* d4 = (const int4*)(dst + eb * HEDGES);
        const float4* w4 = (const float4*)(w + eb * HEDGES);
        for (int i = threadIdx.x; i < HEDGES / 4; i += 256) {
            int4 dv = d4[i]; float4 wv = w4[i];
            unsigned r;
            r = (unsigned)(dv.x - nbase); if (r < HNODES) atomicAdd(&h[r], wv.x);
            r = (unsigned)(dv.y - nbase); if (r < HNODES) atomicAdd(&h[r], wv.y);
            r = (unsigned)(dv.z - nbase); if (r < HNODES) atomicAdd(&h[r], wv.z);
            r = (unsigned)(dv.w - nbase); if (r < HNODES) atomicAdd(&h[r], wv.w);
        }
        __syncthreads();
        float* outp = degp + (size_t)bid * HNODES;
        for (int i = threadIdx.x; i < HNODES; i += 256) outp[i] = h[i];
    } else {
        int slab = bid - 2 * HBLKS;
        int* bc = (int*)h;
        for (int i = threadIdx.x; i < NBUCKET; i += 256) bc[i] = 0;
        __syncthreads();
        const int4* s4 = (const int4*)(src + slab * SLAB_E);
        for (int i = threadIdx.x; i < SLAB_E / 4; i += 256) {
            int4 v = s4[i];
            atomicAdd(&bc[v.x >> 6], 1);
            atomicAdd(&bc[v.y >> 6], 1);
            atomicAdd(&bc[v.z >> 6], 1);
            atomicAdd(&bc[v.w >> 6], 1);
        }
        __syncthreads();
        for (int b = threadIdx.x; b < NBUCKET; b += 256) cnt[b * NSLAB + slab] = bc[b];
    }
}

// K2: (a) blocks [0,313): per-bucket offsets. bbase = flat prefix of cnt
//         (coalesced triangle read) + 256-wide LDS scan of this bucket's slab
//         counts -> off.
//     (b) blocks [313,313+2504): fcT' = dinv*fc_w transpose, dinv computed
//         inline per node via 32-lane shfl reduce of the 64 deg partials.
__global__ __launch_bounds__(256) void k2_prep(const int* __restrict__ cnt,
        int* __restrict__ off, const float* __restrict__ fc_w,
        const float* __restrict__ degp, float* __restrict__ fc_wT,
        float* __restrict__ dinv) {
    int bid = blockIdx.x;
    int t = threadIdx.x;
    if (bid < NBUCKET) {
        __shared__ int lds[256];
        __shared__ int bb;
        int b = bid;
        int s = 0;
        int lim = b * NSLAB;                 // flat prefix: first b*256 counts
        for (int i = t; i < lim; i += 256) s += cnt[i];
        lds[t] = s;
        __syncthreads();
        for (int o = 128; o > 0; o >>= 1) {
            if (t < o) lds[t] += lds[t + o];
            __syncthreads();
        }
        if (t == 0) bb = lds[0];
        __syncthreads();
        int base = bb;
        int v = cnt[b * NSLAB + t];
        lds[t] = v;
        __syncthreads();
        for (int o = 1; o < 256; o <<= 1) {
            int u = (t >= o) ? lds[t - o] : 0;
            __syncthreads();
            lds[t] += u;
            __syncthreads();
        }
        off[b * NSLAB + t] = base + lds[t] - v;      // exclusive prefix
        if (b == NBUCKET - 1 && t == 255) off[NSCAN] = base + lds[t];
    } else {
        int idx = (bid - NBUCKET) * 256 + t;
        int n = idx >> 5, c = idx & 31;
        float v = 0.f;
        if (n < N_NODES) {
            int half = n / HNODES, nn = n - half * HNODES;
            v = degp[(size_t)((c << 1) | half) * HNODES + nn]
              + degp[(size_t)(((c + 32) << 1) | half) * HNODES + nn];
        }
        #pragma unroll
        for (int m = 16; m > 0; m >>= 1) v += __shfl_xor(v, m, 32);
        float di = rsqrtf(v + 1.0f);                 // +1 = self-loop weight
        if (n < N_NODES && c == 0) dinv[n] = di;
        float fw = (n < N_NODES && c < N_CLASSES) ? fc_w[c * N_NODES + n] : 0.f;
        fc_wT[idx] = di * fw;
    }
}

// K3: scatter edges into bucket-partitioned records {(s_local<<15)|d, w_raw}
__global__ __launch_bounds__(512) void k3_scatter(const int* __restrict__ src,
        const int* __restrict__ dst, const float* __restrict__ w,
        const int* __restrict__ off, int2* __restrict__ erec) {
    __shared__ int cur[NBUCKET];
    int slab = blockIdx.x;
    for (int b = threadIdx.x; b < NBUCKET; b += 512) cur[b] = off[b * NSLAB + slab];
    __syncthreads();
    int e0 = slab * SLAB_E;
    const int4* s4 = (const int4*)(src + e0);
    const int4* d4 = (const int4*)(dst + e0);
    const float4* w4 = (const float4*)(w + e0);
    for (int i = threadIdx.x; i < SLAB_E / 4; i += 512) {
        int4 sv = s4[i]; int4 dv = d4[i]; float4 wv = w4[i];
        int s, p;
        s = sv.x; p = atomicAdd(&cur[s >> 6], 1);
        erec[p] = make_int2(((s & 63) << 15) | dv.x, __float_as_int(wv.x));
        s = sv.y; p = atomicAdd(&cur[s >> 6], 1);
        erec[p] = make_int2(((s & 63) << 15) | dv.y, __float_as_int(wv.y));
        s = sv.z; p = atomicAdd(&cur[s >> 6], 1);
        erec[p] = make_int2(((s & 63) << 15) | dv.z, __float_as_int(wv.z));
        s = sv.w; p = atomicAdd(&cur[s >> 6], 1);
        erec[p] = make_int2(((s & 63) << 15) | dv.w, __float_as_int(wv.w));
    }
}

// K4: per-bucket in-LDS counting sort by node, then register-accumulate gather.
__global__ __launch_bounds__(512) void k4_fold(const int2* __restrict__ erec,
        const int* __restrict__ off, const float* __restrict__ dinv,
        const float* __restrict__ fc_wT, float* __restrict__ gT) {
    __shared__ int2 srt[ECAP];        // 20.8 KB
    __shared__ int hist[BN];
    __shared__ int rowst[BN];
    __shared__ int cur[BN];
    int bucket = blockIdx.x;
    int nlo = bucket * BN;
    int bstart = off[bucket * NSLAB];
    int bend   = off[(bucket + 1) * NSLAB];
    int len = min(bend - bstart, ECAP);
    if (threadIdx.x < BN) hist[threadIdx.x] = 0;
    __syncthreads();
    for (int i = threadIdx.x; i < len; i += 512)
        atomicAdd(&hist[((unsigned)erec[bstart + i].x) >> 15], 1);
    __syncthreads();
    if (threadIdx.x < BN) {
        int h = hist[threadIdx.x];
        int v = h;
        #pragma unroll
        for (int o = 1; o < BN; o <<= 1) {
            int u = __shfl_up(v, o, 64);
            if (threadIdx.x >= o) v += u;
        }
        rowst[threadIdx.x] = v - h;
        cur[threadIdx.x]   = v - h;
    }
    __syncthreads();
    for (int i = threadIdx.x; i < len; i += 512) {
        int2 r = erec[bstart + i];
        int p = atomicAdd(&cur[((unsigned)r.x) >> 15], 1);
        srt[p] = r;
    }
    __syncthreads();
    int c = threadIdx.x & 31;
    int grp = threadIdx.x >> 5;
    for (int nn = grp; nn < BN; nn += 16) {
        int n = nlo + nn;
        if (n >= N_NODES) {
            if (n < NPB) gT[(size_t)n * CPAD + c] = 0.f;
            continue;
        }
        float acc  = fc_wT[(size_t)n * CPAD + c];    // self-loop (pre-scaled)
        float acc2 = 0.f;
        int i = rowst[nn], re = i + hist[nn];
        for (; i + 1 < re; i += 2) {
            int2 r0 = srt[i], r1 = srt[i + 1];       // LDS broadcast
            acc  += __int_as_float(r0.y) * fc_wT[(size_t)(r0.x & 0x7FFF) * CPAD + c];
            acc2 += __int_as_float(r1.y) * fc_wT[(size_t)(r1.x & 0x7FFF) * CPAD + c];
        }
        if (i < re) {
            int2 r0 = srt[i];
            acc += __int_as_float(r0.y) * fc_wT[(size_t)(r0.x & 0x7FFF) * CPAD + c];
        }
        gT[(size_t)n * CPAD + c] = dinv[n] * (acc + acc2);
    }
}

// K5: logits partials; each block accumulates 3 strided n-chunks in registers.
__global__ __launch_bounds__(512) void k5_gemm(const float* __restrict__ x,
        const float* __restrict__ gT, float* __restrict__ part) {
    __shared__ float xl[(NCHUNK / 2) * XL_LD];   // 16.6 KB
    __shared__ float gt[CPAD * GT_LD];           //  8.7 KB
    int bx = blockIdx.x, bh = blockIdx.y;
    int b0 = bh * 64;
    int wv = threadIdx.x >> 6, l = threadIdx.x & 63;
    float acc0 = 0.f, acc1 = 0.f, acc2 = 0.f, acc3 = 0.f;
    for (int j = 0; j < 3; j++) {
        int ch = bx + GBX * j;
        if (ch >= NCHUNKS) break;
        int n0 = ch * NCHUNK;
        for (int o = threadIdx.x; o < 64 * NCHUNK; o += 512) {
            int b = o >> 6, n = o & (NCHUNK - 1);
            int gn = n0 + n;
            float v = (gn < N_NODES) ? x[(size_t)(b0 + b) * N_NODES + gn] : 0.f;
            xl[(n >> 1) * XL_LD + b * 2 + (n & 1)] = v;
        }
        for (int o = threadIdx.x; o < NCHUNK * CPAD; o += 512) {
            int n = o >> 5, cc = o & 31;
            gt[cc * GT_LD + n] = gT[(size_t)n0 * CPAD + o];
        }
        __syncthreads();
        #pragma unroll
        for (int n4 = 0; n4 < NCHUNK / 4; n4++) {
            float2 xa = *(const float2*)&xl[(2 * n4) * XL_LD + l * 2];
            float2 xb = *(const float2*)&xl[(2 * n4 + 1) * XL_LD + l * 2];
            float4 ga = *(const float4*)&gt[(wv)      * GT_LD + 4 * n4];
            float4 gb = *(const float4*)&gt[(wv +  8) * GT_LD + 4 * n4];
            float4 gc = *(const float4*)&gt[(wv + 16) * GT_LD + 4 * n4];
            float4 gd = *(const float4*)&gt[(wv + 24) * GT_LD + 4 * n4];
            acc0 += xa.x * ga.x + xa.y * ga.y + xb.x * ga.z + xb.y * ga.w;
            acc1 += xa.x * gb.x + xa.y * gb.y + xb.x * gb.z + xb.y * gb.w;
            acc2 += xa.x * gc.x + xa.y * gc.y + xb.x * gc.z + xb.y * gc.w;
            acc3 += xa.x * gd.x + xa.y * gd.y + xb.x * gd.z + xb.y * gd.w;
        }
        __syncthreads();
    }
    size_t pb = (size_t)(bx * 2 + bh) * CPAD * 64;
    part[pb + (size_t)(wv)      * 64 + l] = acc0;
    part[pb + (size_t)(wv +  8) * 64 + l] = acc1;
    part[pb + (size_t)(wv + 16) * 64 + l] = acc2;
    part[pb + (size_t)(wv + 24) * 64 + l] = acc3;
}

// K6: final reduce + bias + softmax. 2 blocks (one per batch-half), 1024 threads.
__global__ __launch_bounds__(1024) void k6_final(const float* __restrict__ part,
        const float* __restrict__ fc_b, float* __restrict__ out) {
    __shared__ float lg[64 * 33];
    int bh = blockIdx.x;
    int l = threadIdx.x & 63;
    int cq = threadIdx.x >> 6;   // 0..15 -> classes cq, cq+16
    float s0 = 0.f, s1 = 0.f;
    for (int bx = 0; bx < GBX; bx++) {
        const float* p = part + (size_t)(bx * 2 + bh) * CPAD * 64;
        s0 += p[cq * 64 + l];
        s1 += p[(cq + 16) * 64 + l];
    }
    lg[l * 33 + cq]      = s0 + ((cq < N_CLASSES) ? fc_b[cq] : 0.f);
    lg[l * 33 + cq + 16] = s1 + ((cq + 16 < N_CLASSES) ? fc_b[cq + 16] : 0.f);
    __syncthreads();
    if (threadIdx.x < 64) {
        int b = bh * 64 + threadIdx.x;
        float v[N_CLASSES], m = -1e30f;
        #pragma unroll
        for (int c = 0; c < N_CLASSES; c++) {
            v[c] = lg[threadIdx.x * 33 + c];
            m = fmaxf(m, v[c]);
        }
        float s = 0.f;
        #pragma unroll
        for (int c = 0; c < N_CLASSES; c++) { v[c] = __expf(v[c] - m); s += v[c]; }
        float inv = 1.0f / s;
        #pragma unroll
        for (int c = 0; c < N_CLASSES; c++) out[b * N_CLASSES + c] = v[c] * inv;
    }
}

extern "C" void kernel_launch(void* const* d_in, const int* in_sizes, int n_in,
                              void* d_out, int out_size, void* d_ws, size_t ws_size,
                              hipStream_t stream) {
    const float* x          = (const float*)d_in[0];
    const int*   edge_index = (const int*)d_in[1];
    const float* ew         = (const float*)d_in[2];
    const float* fc_w       = (const float*)d_in[3];
    const float* fc_b       = (const float*)d_in[4];
    float* out = (float*)d_out;

    const int* src = edge_index;
    const int* dst = edge_index + N_EDGES_C;

    // ws layout (float slots), time-disjoint aliasing:
    //   A (1,280,000): degp [K1..K2] -> part [K5..K6] (part = 524,288)
    //   B (1,280,000): erec [K3..K4]
    float* A     = (float*)d_ws;                             // 1,280,000
    float* B     = A + 1280000;                              // 1,280,000
    float* dinv  = B + 1280000;                              // 20,000
    int*   cnt   = (int*)(dinv + N_NODES);                   // 80,128
    int*   off   = cnt + NSCAN;                              // 80,129 (pad 80,136)
    float* fc_wT = (float*)(off + 80136);                    // 641,024
    float* gT    = fc_wT + (size_t)NPB * CPAD;               // 641,024

    k1_hists<<<2 * HBLKS + NSLAB, 256, 0, stream>>>(src, dst, ew, A, cnt);
    k2_prep<<<NBUCKET + FCB, 256, 0, stream>>>(cnt, off, fc_w, A, fc_wT, dinv);
    k3_scatter<<<NSLAB, 512, 0, stream>>>(src, dst, ew, off, (int2*)B);
    k4_fold<<<NBUCKET, 512, 0, stream>>>((int2*)B, off, dinv, fc_wT, gT);
    k5_gemm<<<dim3(GBX, 2), 512, 0, stream>>>(x, gT, A);
    k6_final<<<2, 1024, 0, stream>>>(A, fc_b, out);
}

// Round 9
// 92.333 us; speedup vs baseline: 1.3644x; 1.3644x over previous
//
#include <hip/hip_runtime.h>

// DiffuseLR v7: R7 pipeline (proven 101us) + tiled fc_w transpose +
// register-accum gemm + fused final. 7 launches, zero device atomics.
//   gT[s][c] = sum_{e:src=s} wn_e*fc_w[c][dst_e] + dinv[s]^2*fc_w[c][s]
//   logits = x @ gT + b; out = softmax(logits)

#define N_NODES   20000
#define N_EDGES_C 640000
#define N_CLASSES 30
#define CPAD      32

// deg-hist geometry
#define HBLKS     64
#define HNODES    10000
#define HEDGES    (N_EDGES_C / HBLKS)     // 10000

// partition geometry
#define BN        64                      // nodes per bucket
#define NBUCKET   313                     // ceil(20000/64)
#define NPB       (NBUCKET * BN)          // 20032
#define NSLAB     256
#define SLAB_E    (N_EDGES_C / NSLAB)     // 2500
#define NSCAN     (NBUCKET * NSLAB)       // 80128
#define ECAP      2600                    // per-bucket cap (mean 2048, sd ~45)

// gemm geometry
#define NCHUNK    64
#define NCHUNKS   313
#define XL_LD     130
#define GT_LD     68
#define GBX       128                     // gemm grid x; 3 strided chunks each

#define DINVB     ((N_NODES + 255) / 256) // 79

// K1: (a) blocks [0,128): weighted in-degree LDS histogram per (edge-slab, half)
//     (b) blocks [128,384): src-bucket counts per slab (counting-sort pass 1)
__global__ __launch_bounds__(256) void k1_hists(const int* __restrict__ src,
        const int* __restrict__ dst, const float* __restrict__ w,
        float* __restrict__ degp, int* __restrict__ cnt) {
    __shared__ float h[HNODES];   // 40 KB (aliased as int bc[] in role b)
    int bid = blockIdx.x;
    if (bid < 2 * HBLKS) {
        int eb = bid >> 1, half = bid & 1;
        int nbase = half * HNODES;
        for (int i = threadIdx.x; i < HNODES; i += 256) h[i] = 0.f;
        __syncthreads();
        const int4* d4 = (const int4*)(dst + eb * HEDGES);
        const float4* w4 = (const float4*)(w + eb * HEDGES);
        for (int i = threadIdx.x; i < HEDGES / 4; i += 256) {
            int4 dv = d4[i]; float4 wv = w4[i];
            unsigned r;
            r = (unsigned)(dv.x - nbase); if (r < HNODES) atomicAdd(&h[r], wv.x);
            r = (unsigned)(dv.y - nbase); if (r < HNODES) atomicAdd(&h[r], wv.y);
            r = (unsigned)(dv.z - nbase); if (r < HNODES) atomicAdd(&h[r], wv.z);
            r = (unsigned)(dv.w - nbase); if (r < HNODES) atomicAdd(&h[r], wv.w);
        }
        __syncthreads();
        float* outp = degp + (size_t)bid * HNODES;
        for (int i = threadIdx.x; i < HNODES; i += 256) outp[i] = h[i];
    } else {
        int slab = bid - 2 * HBLKS;
        int* bc = (int*)h;
        for (int i = threadIdx.x; i < NBUCKET; i += 256) bc[i] = 0;
        __syncthreads();
        const int4* s4 = (const int4*)(src + slab * SLAB_E);
        for (int i = threadIdx.x; i < SLAB_E / 4; i += 256) {
            int4 v = s4[i];
            atomicAdd(&bc[v.x >> 6], 1);
            atomicAdd(&bc[v.y >> 6], 1);
            atomicAdd(&bc[v.z >> 6], 1);
            atomicAdd(&bc[v.w >> 6], 1);
        }
        __syncthreads();
        for (int b = threadIdx.x; b < NBUCKET; b += 256) cnt[b * NSLAB + slab] = bc[b];
    }
}

// K2: (a) blocks [0,313): btot[b] = sum_slab cnt[b][slab]
//     (b) blocks [313,626): LDS-tiled fc_w transpose (64 nodes/block, coalesced)
//     (c) blocks [626,705): dinv = rsqrt(1+deg), coalesced serial slab loop
__global__ __launch_bounds__(256) void k2_prep(const int* __restrict__ cnt,
        int* __restrict__ btot, const float* __restrict__ fc_w,
        const float* __restrict__ degp, float* __restrict__ fc_wT,
        float* __restrict__ dinv) {
    int bid = blockIdx.x;
    int t = threadIdx.x;
    if (bid < NBUCKET) {
        __shared__ int lds[256];
        lds[t] = cnt[bid * NSLAB + t];
        __syncthreads();
        for (int o = 128; o > 0; o >>= 1) {
            if (t < o) lds[t] += lds[t + o];
            __syncthreads();
        }
        if (t == 0) btot[bid] = lds[0];
    } else if (bid < 2 * NBUCKET) {
        __shared__ float tile[CPAD][65];
        int n0 = (bid - NBUCKET) * 64;
        #pragma unroll
        for (int k = 0; k < 8; k++) {           // rows c = k*4 + (t>>6)
            int c = k * 4 + (t >> 6), nn = t & 63;
            int n = n0 + nn;
            tile[c][nn] = (c < N_CLASSES && n < N_NODES) ? fc_w[c * N_NODES + n] : 0.f;
        }
        __syncthreads();
        #pragma unroll
        for (int k = 0; k < 8; k++) {           // write 64 nodes x 32 classes
            int idx = k * 256 + t;
            int nn = idx >> 5, c = idx & 31;
            fc_wT[(size_t)(n0 + nn) * CPAD + c] = tile[c][nn];
        }
    } else {
        int n = (bid - 2 * NBUCKET) * 256 + t;
        if (n < N_NODES) {
            int half = n / HNODES, nn = n - half * HNODES;
            float s = 1.0f;   // self-loop weight
            for (int eb = 0; eb < HBLKS; eb++)
                s += degp[(size_t)((eb << 1) | half) * HNODES + nn];
            dinv[n] = rsqrtf(s);
        }
    }
}

// K3: per-bucket offsets. Block b: bbase = sum_{b'<b} btot[b'] (313-wide reduce),
// then 256-wide LDS scan of cnt[b][*] -> off[b*NSLAB+slab].
__global__ __launch_bounds__(256) void k3_off(const int* __restrict__ cnt,
        const int* __restrict__ btot, int* __restrict__ off) {
    __shared__ int lds[256];
    __shared__ int bb;
    int b = blockIdx.x, t = threadIdx.x;
    int s = 0;
    for (int i = t; i < b; i += 256) s += btot[i];
    lds[t] = s;
    __syncthreads();
    for (int o = 128; o > 0; o >>= 1) {
        if (t < o) lds[t] += lds[t + o];
        __syncthreads();
    }
    if (t == 0) bb = lds[0];
    __syncthreads();
    int base = bb;
    int v = cnt[b * NSLAB + t];
    lds[t] = v;
    __syncthreads();
    for (int o = 1; o < 256; o <<= 1) {
        int u = (t >= o) ? lds[t - o] : 0;
        __syncthreads();
        lds[t] += u;
        __syncthreads();
    }
    off[b * NSLAB + t] = base + lds[t] - v;          // exclusive prefix
    if (b == NBUCKET - 1 && t == 255) off[NSCAN] = base + lds[t];
}

// K4: scatter edges into bucket-partitioned records {(s_local<<15)|d, wn}
// (dinv is 80 KB -> L1/L2 resident; random reads proven cheap in R7)
__global__ __launch_bounds__(512) void k4_scatter(const int* __restrict__ src,
        const int* __restrict__ dst, const float* __restrict__ w,
        const float* __restrict__ dinv, const int* __restrict__ off,
        int2* __restrict__ erec) {
    __shared__ int cur[NBUCKET];
    int slab = blockIdx.x;
    for (int b = threadIdx.x; b < NBUCKET; b += 512) cur[b] = off[b * NSLAB + slab];
    __syncthreads();
    int e0 = slab * SLAB_E;
    const int4* s4 = (const int4*)(src + e0);
    const int4* d4 = (const int4*)(dst + e0);
    const float4* w4 = (const float4*)(w + e0);
    for (int i = threadIdx.x; i < SLAB_E / 4; i += 512) {
        int4 sv = s4[i]; int4 dv = d4[i]; float4 wv = w4[i];
        int s, d, p; float wn;
        s = sv.x; d = dv.x; wn = dinv[s] * wv.x * dinv[d];
        p = atomicAdd(&cur[s >> 6], 1);
        erec[p] = make_int2(((s & 63) << 15) | d, __float_as_int(wn));
        s = sv.y; d = dv.y; wn = dinv[s] * wv.y * dinv[d];
        p = atomicAdd(&cur[s >> 6], 1);
        erec[p] = make_int2(((s & 63) << 15) | d, __float_as_int(wn));
        s = sv.z; d = dv.z; wn = dinv[s] * wv.z * dinv[d];
        p = atomicAdd(&cur[s >> 6], 1);
        erec[p] = make_int2(((s & 63) << 15) | d, __float_as_int(wn));
        s = sv.w; d = dv.w; wn = dinv[s] * wv.w * dinv[d];
        p = atomicAdd(&cur[s >> 6], 1);
        erec[p] = make_int2(((s & 63) << 15) | d, __float_as_int(wn));
    }
}

// K5: per-bucket in-LDS counting sort by node, then register-accumulate gather.
__global__ __launch_bounds__(512) void k5_fold(const int2* __restrict__ erec,
        const int* __restrict__ off, const float* __restrict__ dinv,
        const float* __restrict__ fc_wT, float* __restrict__ gT) {
    __shared__ int2 srt[ECAP];        // 20.8 KB
    __shared__ int hist[BN];
    __shared__ int rowst[BN];
    __shared__ int cur[BN];
    int bucket = blockIdx.x;
    int nlo = bucket * BN;
    int bstart = off[bucket * NSLAB];
    int bend   = off[(bucket + 1) * NSLAB];
    int len = min(bend - bstart, ECAP);
    if (threadIdx.x < BN) hist[threadIdx.x] = 0;
    __syncthreads();
    for (int i = threadIdx.x; i < len; i += 512)
        atomicAdd(&hist[((unsigned)erec[bstart + i].x) >> 15], 1);
    __syncthreads();
    if (threadIdx.x < BN) {
        int h = hist[threadIdx.x];
        int v = h;
        #pragma unroll
        for (int o = 1; o < BN; o <<= 1) {
            int u = __shfl_up(v, o, 64);
            if (threadIdx.x >= o) v += u;
        }
        rowst[threadIdx.x] = v - h;
        cur[threadIdx.x]   = v - h;
    }
    __syncthreads();
    for (int i = threadIdx.x; i < len; i += 512) {
        int2 r = erec[bstart + i];
        int p = atomicAdd(&cur[((unsigned)r.x) >> 15], 1);
        srt[p] = r;
    }
    __syncthreads();
    int c = threadIdx.x & 31;
    int grp = threadIdx.x >> 5;
    for (int nn = grp; nn < BN; nn += 16) {
        int n = nlo + nn;
        if (n >= N_NODES) {
            if (n < NPB) gT[(size_t)n * CPAD + c] = 0.f;
            continue;
        }
        float di = dinv[n];
        float acc  = di * di * fc_wT[(size_t)n * CPAD + c];   // self-loop
        float acc2 = 0.f;
        int i = rowst[nn], re = i + hist[nn];
        for (; i + 1 < re; i += 2) {
            int2 r0 = srt[i], r1 = srt[i + 1];                // LDS broadcast
            acc  += __int_as_float(r0.y) * fc_wT[(size_t)(r0.x & 0x7FFF) * CPAD + c];
            acc2 += __int_as_float(r1.y) * fc_wT[(size_t)(r1.x & 0x7FFF) * CPAD + c];
        }
        if (i < re) {
            int2 r0 = srt[i];
            acc += __int_as_float(r0.y) * fc_wT[(size_t)(r0.x & 0x7FFF) * CPAD + c];
        }
        gT[(size_t)n * CPAD + c] = acc + acc2;
    }
}

// K6: logits partials; each block accumulates 3 strided n-chunks in registers.
__global__ __launch_bounds__(512) void k6_gemm(const float* __restrict__ x,
        const float* __restrict__ gT, float* __restrict__ part) {
    __shared__ float xl[(NCHUNK / 2) * XL_LD];   // 16.6 KB
    __shared__ float gt[CPAD * GT_LD];           //  8.7 KB
    int bx = blockIdx.x, bh = blockIdx.y;
    int b0 = bh * 64;
    int wv = threadIdx.x >> 6, l = threadIdx.x & 63;
    float acc0 = 0.f, acc1 = 0.f, acc2 = 0.f, acc3 = 0.f;
    for (int j = 0; j < 3; j++) {
        int ch = bx + GBX * j;
        if (ch >= NCHUNKS) break;
        int n0 = ch * NCHUNK;
        for (int o = threadIdx.x; o < 64 * NCHUNK; o += 512) {
            int b = o >> 6, n = o & (NCHUNK - 1);
            int gn = n0 + n;
            float v = (gn < N_NODES) ? x[(size_t)(b0 + b) * N_NODES + gn] : 0.f;
            xl[(n >> 1) * XL_LD + b * 2 + (n & 1)] = v;
        }
        for (int o = threadIdx.x; o < NCHUNK * CPAD; o += 512) {
            int n = o >> 5, cc = o & 31;
            gt[cc * GT_LD + n] = gT[(size_t)n0 * CPAD + o];
        }
        __syncthreads();
        #pragma unroll
        for (int n4 = 0; n4 < NCHUNK / 4; n4++) {
            float2 xa = *(const float2*)&xl[(2 * n4) * XL_LD + l * 2];
            float2 xb = *(const float2*)&xl[(2 * n4 + 1) * XL_LD + l * 2];
            float4 ga = *(const float4*)&gt[(wv)      * GT_LD + 4 * n4];
            float4 gb = *(const float4*)&gt[(wv +  8) * GT_LD + 4 * n4];
            float4 gc = *(const float4*)&gt[(wv + 16) * GT_LD + 4 * n4];
            float4 gd = *(const float4*)&gt[(wv + 24) * GT_LD + 4 * n4];
            acc0 += xa.x * ga.x + xa.y * ga.y + xb.x * ga.z + xb.y * ga.w;
            acc1 += xa.x * gb.x + xa.y * gb.y + xb.x * gb.z + xb.y * gb.w;
            acc2 += xa.x * gc.x + xa.y * gc.y + xb.x * gc.z + xb.y * gc.w;
            acc3 += xa.x * gd.x + xa.y * gd.y + xb.x * gd.z + xb.y * gd.w;
        }
        __syncthreads();
    }
    size_t pb = (size_t)(bx * 2 + bh) * CPAD * 64;
    part[pb + (size_t)(wv)      * 64 + l] = acc0;
    part[pb + (size_t)(wv +  8) * 64 + l] = acc1;
    part[pb + (size_t)(wv + 16) * 64 + l] = acc2;
    part[pb + (size_t)(wv + 24) * 64 + l] = acc3;
}

// K7: final reduce + bias + softmax. 2 blocks (one per batch-half), 1024 threads.
__global__ __launch_bounds__(1024) void k7_final(const float* __restrict__ part,
        const float* __restrict__ fc_b, float* __restrict__ out) {
    __shared__ float lg[64 * 33];
    int bh = blockIdx.x;
    int l = threadIdx.x & 63;
    int cq = threadIdx.x >> 6;   // 0..15 -> classes cq, cq+16
    float s0 = 0.f, s1 = 0.f;
    for (int bx = 0; bx < GBX; bx++) {
        const float* p = part + (size_t)(bx * 2 + bh) * CPAD * 64;
        s0 += p[cq * 64 + l];
        s1 += p[(cq + 16) * 64 + l];
    }
    lg[l * 33 + cq]      = s0 + ((cq < N_CLASSES) ? fc_b[cq] : 0.f);
    lg[l * 33 + cq + 16] = s1 + ((cq + 16 < N_CLASSES) ? fc_b[cq + 16] : 0.f);
    __syncthreads();
    if (threadIdx.x < 64) {
        int b = bh * 64 + threadIdx.x;
        float v[N_CLASSES], m = -1e30f;
        #pragma unroll
        for (int c = 0; c < N_CLASSES; c++) {
            v[c] = lg[threadIdx.x * 33 + c];
            m = fmaxf(m, v[c]);
        }
        float s = 0.f;
        #pragma unroll
        for (int c = 0; c < N_CLASSES; c++) { v[c] = __expf(v[c] - m); s += v[c]; }
        float inv = 1.0f / s;
        #pragma unroll
        for (int c = 0; c < N_CLASSES; c++) out[b * N_CLASSES + c] = v[c] * inv;
    }
}

extern "C" void kernel_launch(void* const* d_in, const int* in_sizes, int n_in,
                              void* d_out, int out_size, void* d_ws, size_t ws_size,
                              hipStream_t stream) {
    const float* x          = (const float*)d_in[0];
    const int*   edge_index = (const int*)d_in[1];
    const float* ew         = (const float*)d_in[2];
    const float* fc_w       = (const float*)d_in[3];
    const float* fc_b       = (const float*)d_in[4];
    float* out = (float*)d_out;

    const int* src = edge_index;
    const int* dst = edge_index + N_EDGES_C;

    // ws layout (float slots), time-disjoint aliasing:
    //   A (1,280,000): degp [K1..K2] -> part [K6..K7] (part = 524,288)
    //   B (1,280,000): erec [K4..K5]
    float* A     = (float*)d_ws;                             // 1,280,000
    float* B     = A + 1280000;                              // 1,280,000
    float* dinv  = B + 1280000;                              // 20,000
    int*   cnt   = (int*)(dinv + N_NODES);                   // 80,128
    int*   off   = cnt + NSCAN;                              // 80,129 (pad 80,136)
    int*   btot  = off + 80136;                              // 313 (pad 320)
    float* fc_wT = (float*)(btot + 320);                     // 641,024
    float* gT    = fc_wT + (size_t)NPB * CPAD;               // 641,024

    k1_hists<<<2 * HBLKS + NSLAB, 256, 0, stream>>>(src, dst, ew, A, cnt);
    k2_prep<<<2 * NBUCKET + DINVB, 256, 0, stream>>>(cnt, btot, fc_w, A,
                                                     fc_wT, dinv);
    k3_off<<<NBUCKET, 256, 0, stream>>>(cnt, btot, off);
    k4_scatter<<<NSLAB, 512, 0, stream>>>(src, dst, ew, dinv, off, (int2*)B);
    k5_fold<<<NBUCKET, 512, 0, stream>>>((int2*)B, off, dinv, fc_wT, gT);
    k6_gemm<<<dim3(GBX, 2), 512, 0, stream>>>(x, gT, A);
    k7_final<<<2, 1024, 0, stream>>>(A, fc_b, out);
}